// Round 1
// baseline (298.085 us; speedup 1.0000x reference)
//
#include <hip/hip_runtime.h>
#include <stdint.h>

// ---------------------------------------------------------------------------
// CrossAttention (b=16, c=1024, dim=1024), fp32 in/out, bf16 MFMA internally.
// Pipeline:
//   1. cvt fp32->bf16: x->XB, cond->CB, Wq->WQB, Wkv->WKVB
//   2. Q  = XB @ WQB^T                      (bf16 out)
//   3. KV = CB @ WKVB^T  -> K (bf16), V^T (bf16, transposed in epilogue)
//   4. S  = Q @ K^T * 1/32  per batch       (fp32 out, overlays XB/CB)
//   5. P  = softmax_rows(S)                 (bf16, overlays Q)
//   6. out= P @ (V^T)^T  per batch          (fp32 -> d_out)
// All GEMMs are A·B^T with K contiguous on both operands.
// ---------------------------------------------------------------------------

typedef __bf16 bf16_t;
typedef bf16_t bf16x8 __attribute__((ext_vector_type(8)));
typedef float f32x4 __attribute__((ext_vector_type(4)));

#define AS1 __attribute__((address_space(1)))
#define AS3 __attribute__((address_space(3)))

__device__ __forceinline__ uint16_t f2bf(float f) {
  bf16_t h = (bf16_t)f;                 // RNE
  return __builtin_bit_cast(uint16_t, h);
}

// ---- fp32 -> bf16 conversion, float4-vectorized ----
__global__ __launch_bounds__(256) void cvt_bf16(const float* __restrict__ in,
                                                uint16_t* __restrict__ out, int n4) {
  int i = blockIdx.x * 256 + threadIdx.x;
  if (i >= n4) return;
  float4 v = ((const float4*)in)[i];
  ushort4 o;
  o.x = f2bf(v.x); o.y = f2bf(v.y); o.z = f2bf(v.z); o.w = f2bf(v.w);
  ((ushort4*)out)[i] = o;
}

// ---- stage one 128x64 bf16 tile (16 KiB) global -> LDS via global_load_lds ----
// LDS dest is linear; global SOURCE is chunk-XOR-pre-swizzled (rule #21) so the
// reader's  byte^=((row&7)<<4)  swizzle sees the right data, bank-conflict-free.
__device__ __forceinline__ void stage_tile(const uint16_t* __restrict__ g, int ld,
                                           uint8_t* lds, int tid) {
  const int lane = tid & 63;
  const int wb = tid & ~63;  // wave-uniform
#pragma unroll
  for (int i = 0; i < 4; ++i) {
    int cidx = i * 256 + wb + lane;     // 16B-chunk index, 0..1023
    int row = cidx >> 3;                // 0..127
    int ch  = cidx & 7;                 // chunk within 128B row
    int sch = ch ^ (row & 7);           // involutive source swizzle
    const uint16_t* gp = g + row * ld + sch * 8;
    __builtin_amdgcn_global_load_lds((AS1 void*)gp, (AS3 void*)(lds + cidx * 16),
                                     16, 0, 0);
  }
}

// ---- generic 128x128-tile A·B^T GEMM, bf16 in, fp32 accum ----
// MODE 0: C0 = bf16, ldc = N
// MODE 1: kv-split epilogue: col<1024 -> K (bf16, row-major); col>=1024 -> V^T
// MODE 2: C0 = fp32 * scale, ldc = N (batched via blockIdx.z, strides in elems)
template <int MODE>
__global__ __launch_bounds__(256, 2) void gemm_bt(
    const uint16_t* __restrict__ A, const uint16_t* __restrict__ B,
    void* __restrict__ C0, void* __restrict__ C1, int K, int N,
    long long sA, long long sB, long long sC, float scale) {
  __shared__ uint8_t smem[2][2][16384];  // [dbuf][A/B][128x64 bf16]

  const int tid  = threadIdx.x;
  const int lane = tid & 63;
  const int wid  = tid >> 6;
  const int wr   = wid >> 1, wc = wid & 1;   // 2x2 wave grid, 64x64 each
  const int lr   = lane & 15, lg = lane >> 4;

  const int row0 = blockIdx.y * 128;
  const int col0 = blockIdx.x * 128;
  const int bz   = blockIdx.z;
  const uint16_t* At = A + (long long)bz * sA + (long long)row0 * K;
  const uint16_t* Bt = B + (long long)bz * sB + (long long)col0 * K;

  f32x4 acc[4][4] = {};

  const int KT = K >> 6;  // 64-wide K tiles
  int cur = 0;
  stage_tile(At, K, &smem[0][0][0], tid);
  stage_tile(Bt, K, &smem[0][1][0], tid);
  __syncthreads();

  for (int kt = 0; kt < KT; ++kt) {
    if (kt + 1 < KT) {  // prefetch next K-tile into the other buffer
      stage_tile(At + (kt + 1) * 64, K, &smem[cur ^ 1][0][0], tid);
      stage_tile(Bt + (kt + 1) * 64, K, &smem[cur ^ 1][1][0], tid);
    }
    const uint8_t* sA_ = &smem[cur][0][0];
    const uint8_t* sB_ = &smem[cur][1][0];
#pragma unroll
    for (int kk = 0; kk < 2; ++kk) {
      bf16x8 fa[4], fb[4];
#pragma unroll
      for (int mi = 0; mi < 4; ++mi) {
        int r = wr * 64 + mi * 16 + lr;
        int byte = r * 128 + (((kk * 4 + lg) ^ (r & 7)) << 4);
        fa[mi] = *(const bf16x8*)(sA_ + byte);
      }
#pragma unroll
      for (int ni = 0; ni < 4; ++ni) {
        int r = wc * 64 + ni * 16 + lr;
        int byte = r * 128 + (((kk * 4 + lg) ^ (r & 7)) << 4);
        fb[ni] = *(const bf16x8*)(sB_ + byte);
      }
#pragma unroll
      for (int mi = 0; mi < 4; ++mi)
#pragma unroll
        for (int ni = 0; ni < 4; ++ni)
          acc[mi][ni] = __builtin_amdgcn_mfma_f32_16x16x32_bf16(
              fa[mi], fb[ni], acc[mi][ni], 0, 0, 0);
    }
    __syncthreads();  // drains vmcnt (stage) + lgkm (reads); swap buffers
    cur ^= 1;
  }

  // epilogue: C/D layout col=lane&15, row=(lane>>4)*4+j  [m89/m91 verified]
#pragma unroll
  for (int mi = 0; mi < 4; ++mi) {
#pragma unroll
    for (int ni = 0; ni < 4; ++ni) {
      const int row = row0 + wr * 64 + mi * 16 + lg * 4;  // +j
      const int col = col0 + wc * 64 + ni * 16 + lr;
      if (MODE == 0) {
        uint16_t* C = (uint16_t*)C0;
#pragma unroll
        for (int j = 0; j < 4; ++j)
          C[(long long)(row + j) * N + col] = f2bf(acc[mi][ni][j]);
      } else if (MODE == 1) {
        const int b = row >> 10, jj = row & 1023;  // uniform within fragment
        if (col < 1024) {
          uint16_t* Kp = (uint16_t*)C0;
#pragma unroll
          for (int j = 0; j < 4; ++j)
            Kp[(long long)(row + j) * 1024 + col] = f2bf(acc[mi][ni][j]);
        } else {
          ushort4 o;
          o.x = f2bf(acc[mi][ni][0]);
          o.y = f2bf(acc[mi][ni][1]);
          o.z = f2bf(acc[mi][ni][2]);
          o.w = f2bf(acc[mi][ni][3]);
          uint16_t* Vp = (uint16_t*)C1;
          *(ushort4*)(Vp + (long long)b * 1048576 +
                      (long long)(col - 1024) * 1024 + jj) = o;
        }
      } else {
        float* C = (float*)C0;
#pragma unroll
        for (int j = 0; j < 4; ++j)
          C[(long long)bz * sC + (long long)(row + j) * N + col] =
              acc[mi][ni][j] * scale;
      }
    }
  }
}

// ---- row softmax: 16384 rows x 1024 fp32 -> bf16 ----
__global__ __launch_bounds__(256) void softmax_rows(const float* __restrict__ S,
                                                    uint16_t* __restrict__ P) {
  const int row = blockIdx.x;
  const int t = threadIdx.x;
  const int w = t >> 6, l = t & 63;
  __shared__ float red[8];

  const float4 v = ((const float4*)(S + (long long)row * 1024))[t];
  float m = fmaxf(fmaxf(v.x, v.y), fmaxf(v.z, v.w));
#pragma unroll
  for (int o = 1; o < 64; o <<= 1) m = fmaxf(m, __shfl_xor(m, o, 64));
  if (l == 0) red[w] = m;
  __syncthreads();
  m = fmaxf(fmaxf(red[0], red[1]), fmaxf(red[2], red[3]));

  float e0 = __expf(v.x - m), e1 = __expf(v.y - m);
  float e2 = __expf(v.z - m), e3 = __expf(v.w - m);
  float s = e0 + e1 + e2 + e3;
#pragma unroll
  for (int o = 1; o < 64; o <<= 1) s += __shfl_xor(s, o, 64);
  if (l == 0) red[4 + w] = s;
  __syncthreads();
  s = red[4] + red[5] + red[6] + red[7];
  const float inv = 1.0f / s;

  ushort4 o4;
  o4.x = f2bf(e0 * inv); o4.y = f2bf(e1 * inv);
  o4.z = f2bf(e2 * inv); o4.w = f2bf(e3 * inv);
  ((ushort4*)P)[(long long)row * 256 + t] = o4;
}

extern "C" void kernel_launch(void* const* d_in, const int* in_sizes, int n_in,
                              void* d_out, int out_size, void* d_ws, size_t ws_size,
                              hipStream_t stream) {
  const float* x    = (const float*)d_in[0];
  const float* cond = (const float*)d_in[1];
  const float* Wq   = (const float*)d_in[2];
  const float* Wkv  = (const float*)d_in[3];
  float* out = (float*)d_out;

  uint8_t* ws = (uint8_t*)d_ws;
  const long long MiB = 1ll << 20;
  // layout (166 MiB peak): S(fp32,64Mi) overlays XB+CB; P overlays Q.
  uint16_t* XB   = (uint16_t*)(ws + 0 * MiB);    // 32 MiB
  uint16_t* CB   = (uint16_t*)(ws + 32 * MiB);   // 32 MiB
  float*    S    = (float*)(ws + 0 * MiB);       // 64 MiB (after projections)
  uint16_t* WQB  = (uint16_t*)(ws + 64 * MiB);   // 2 MiB
  uint16_t* WKVB = (uint16_t*)(ws + 66 * MiB);   // 4 MiB
  uint16_t* Q    = (uint16_t*)(ws + 70 * MiB);   // 32 MiB (later P)
  uint16_t* Kb   = (uint16_t*)(ws + 102 * MiB);  // 32 MiB
  uint16_t* VT   = (uint16_t*)(ws + 134 * MiB);  // 32 MiB

  // 1. conversions
  cvt_bf16<<<16384, 256, 0, stream>>>(x, XB, 16777216 / 4);
  cvt_bf16<<<16384, 256, 0, stream>>>(cond, CB, 16777216 / 4);
  cvt_bf16<<<1024, 256, 0, stream>>>(Wq, WQB, 1048576 / 4);
  cvt_bf16<<<2048, 256, 0, stream>>>(Wkv, WKVB, 2097152 / 4);

  // 2. Q = XB @ WQB^T   (M=16384, N=1024, K=1024)
  gemm_bt<0><<<dim3(8, 128, 1), 256, 0, stream>>>(XB, WQB, Q, nullptr, 1024, 1024,
                                                  0, 0, 0, 1.0f);
  // 3. KV = CB @ WKVB^T (M=16384, N=2048) -> K, V^T
  gemm_bt<1><<<dim3(16, 128, 1), 256, 0, stream>>>(CB, WKVB, Kb, VT, 1024, 2048,
                                                   0, 0, 0, 1.0f);
  // 4. S = Q @ K^T * 1/32, batched over 16
  gemm_bt<2><<<dim3(8, 8, 16), 256, 0, stream>>>(Q, Kb, S, nullptr, 1024, 1024,
                                                 1048576, 1048576, 1048576,
                                                 0.03125f);
  // 5. P = softmax(S) -> bf16, overlays Q
  softmax_rows<<<16384, 256, 0, stream>>>(S, Q);
  // 6. out = P @ (V^T)^T, batched over 16
  gemm_bt<2><<<dim3(8, 8, 16), 256, 0, stream>>>(Q, VT, out, nullptr, 1024, 1024,
                                                 1048576, 1048576, 1048576, 1.0f);
}

// Round 2
// 269.192 us; speedup vs baseline: 1.1073x; 1.1073x over previous
//
#include <hip/hip_runtime.h>
#include <stdint.h>

// ---------------------------------------------------------------------------
// CrossAttention (b=16, c=1024, dim=1024), fp32 in/out, bf16 MFMA internally.
//   1. cvt fp32->bf16: x->XB, cond->CB, Wq->WQB, Wkv->WKVB
//   2. Q  = XB @ WQB^T                      (bf16 out)
//   3. KV = CB @ WKVB^T  -> K (bf16), V^T   (bf16, transposed in epilogue)
//   4. S  = Q @ K^T * 1/32  per batch       (fp32, overlays XB/CB)
//   5. P  = softmax_rows(S)                 (bf16, overlays Q)
//   6. out= P @ (V^T)^T  per batch          (fp32 -> d_out)
// GEMM: 256x256 tile, BK=64, 8 waves (2Mx4N), 4-phase/K-tile schedule with
// counted vmcnt (T3+T4), XOR-swizzled LDS (T2), setprio around MFMA (T5).
// ---------------------------------------------------------------------------

typedef __bf16 bf16_t;
typedef bf16_t bf16x8 __attribute__((ext_vector_type(8)));
typedef float f32x4 __attribute__((ext_vector_type(4)));

#define AS1 __attribute__((address_space(1)))
#define AS3 __attribute__((address_space(3)))

__device__ __forceinline__ uint16_t f2bf(float f) {
  bf16_t h = (bf16_t)f;  // RNE
  return __builtin_bit_cast(uint16_t, h);
}

// ---- fp32 -> bf16 conversion, float4-vectorized ----
__global__ __launch_bounds__(256) void cvt_bf16(const float* __restrict__ in,
                                                uint16_t* __restrict__ out, int n4) {
  int i = blockIdx.x * 256 + threadIdx.x;
  if (i >= n4) return;
  float4 v = ((const float4*)in)[i];
  ushort4 o;
  o.x = f2bf(v.x); o.y = f2bf(v.y); o.z = f2bf(v.z); o.w = f2bf(v.w);
  ((ushort4*)out)[i] = o;
}

// ---- stage one 128x64 bf16 half-tile (16 KiB) global -> LDS ----
// LDS dest linear (global_load_lds requirement); global SOURCE chunk-XOR
// pre-swizzled (rule #21) so readers use byte^=((row&7)<<4), conflict-free.
// 512 threads x 2 chunks x 16B = 16 KiB. 2 vmem instructions per wave.
__device__ __forceinline__ void stage_half(const uint16_t* __restrict__ g, int ld,
                                           uint8_t* lds, int tid) {
#pragma unroll
  for (int i = 0; i < 2; ++i) {
    int c = i * 512 + tid;              // 16B-chunk index, 0..1023
    int row = c >> 3;                   // 0..127
    int ch = c & 7;                     // chunk within 128B row
    int sch = ch ^ (row & 7);           // involutive source swizzle
    const uint16_t* gp = g + row * ld + sch * 8;
    __builtin_amdgcn_global_load_lds((AS1 void*)gp, (AS3 void*)(lds + c * 16),
                                     16, 0, 0);
  }
}

// ---- 256x256-tile A·B^T GEMM, bf16 in, fp32 accum, 4-phase pipelined ----
// MODE 0: C0 = bf16, ldc = N
// MODE 1: kv-split: col<1024 -> K (bf16 row-major); col>=1024 -> V^T
// MODE 2: C0 = fp32 * scale, batched via blockIdx.z (strides in elements)
template <int MODE>
__global__ __launch_bounds__(512, 2) void gemm_bt(
    const uint16_t* __restrict__ A, const uint16_t* __restrict__ B,
    void* __restrict__ C0, void* __restrict__ C1, int K, int N,
    long long sA, long long sB, long long sC, float scale) {
  // [dbuf][half: rows h*128..h*128+127][128x64 bf16]  -> 128 KiB total
  __shared__ uint16_t As[2][2][8192];
  __shared__ uint16_t Bs[2][2][8192];

  const int tid = threadIdx.x;
  const int lane = tid & 63;
  const int wid = tid >> 6;   // 0..7
  const int wr = wid >> 2;    // 0..1 : M wave row (128 rows each)
  const int wc = wid & 3;     // 0..3 : N wave col (64 cols each)
  const int lr = lane & 15, lg = lane >> 4;
  const int ch0 = lr & 7;     // reader swizzle parity (== row&7 for all frags)

  const int row0 = blockIdx.y * 256;
  const int col0 = blockIdx.x * 256;
  const int bz = blockIdx.z;
  const uint16_t* At = A + (long long)bz * sA + (long long)row0 * K;
  const uint16_t* Bt = B + (long long)bz * sB + (long long)col0 * K;

  const int NT = K >> 6;  // # of 64-wide K tiles (16 here)

  // ---- prologue: stage tile0 (A,B) + tile1 (A) => 6 half-tiles, 12 loads ----
  stage_half(At, K, (uint8_t*)&As[0][0][0], tid);
  stage_half(At + 128 * K, K, (uint8_t*)&As[0][1][0], tid);
  stage_half(Bt, K, (uint8_t*)&Bs[0][0][0], tid);
  stage_half(Bt + 128 * K, K, (uint8_t*)&Bs[0][1][0], tid);
  if (NT > 1) {
    stage_half(At + 64, K, (uint8_t*)&As[1][0][0], tid);
    stage_half(At + 128 * K + 64, K, (uint8_t*)&As[1][1][0], tid);
    asm volatile("s_waitcnt vmcnt(4)" ::: "memory");  // tile0 landed; A1 flies
  } else {
    asm volatile("s_waitcnt vmcnt(0)" ::: "memory");
  }
  asm volatile("s_barrier" ::: "memory");

  f32x4 acc[8][4] = {};

  for (int t = 0; t < NT; ++t) {
    const int buf = t & 1;
    // ---- phase-0 A-fragment burst: 16 x ds_read_b128 (held across phases) --
    bf16x8 fa[8][2];
    const uint8_t* abase = (const uint8_t*)&As[buf][wr][0];
#pragma unroll
    for (int mi = 0; mi < 8; ++mi) {
      const int rr = mi * 16 + lr;
#pragma unroll
      for (int kk = 0; kk < 2; ++kk)
        fa[mi][kk] =
            *(const bf16x8*)(abase + rr * 128 + (((kk * 4 + lg) ^ ch0) << 4));
    }
    const uint8_t* bbase = (const uint8_t*)&Bs[buf][wc >> 1][0];
#pragma unroll
    for (int ni = 0; ni < 4; ++ni) {
      // B fragments for this phase (2 x ds_read_b128)
      const int rb = (wc & 1) * 64 + ni * 16 + lr;
      bf16x8 fb[2];
#pragma unroll
      for (int kk = 0; kk < 2; ++kk)
        fb[kk] =
            *(const bf16x8*)(bbase + rb * 128 + (((kk * 4 + lg) ^ ch0) << 4));
      // stage one half-tile (prefetch stream, ~1.5 tiles ahead):
      //  ph0: B-lo(t+1) -> other buf (its B last read at tile t-1 ph3)
      //  ph1: B-hi(t+1) -> other buf
      //  ph2: A-lo(t+2) -> THIS buf  (A last read in ph0's burst)
      //  ph3: A-hi(t+2) -> THIS buf
      if (ni == 0 && t + 1 < NT)
        stage_half(Bt + (t + 1) * 64, K, (uint8_t*)&Bs[buf ^ 1][0][0], tid);
      if (ni == 1 && t + 1 < NT)
        stage_half(Bt + 128 * K + (t + 1) * 64, K, (uint8_t*)&Bs[buf ^ 1][1][0],
                   tid);
      if (ni == 2 && t + 2 < NT)
        stage_half(At + (t + 2) * 64, K, (uint8_t*)&As[buf][0][0], tid);
      if (ni == 3 && t + 2 < NT)
        stage_half(At + 128 * K + (t + 2) * 64, K, (uint8_t*)&As[buf][1][0],
                   tid);
      asm volatile("s_barrier" ::: "memory");
      __builtin_amdgcn_s_setprio(1);
#pragma unroll
      for (int kk = 0; kk < 2; ++kk)
#pragma unroll
        for (int mi = 0; mi < 8; ++mi)
          acc[mi][ni] = __builtin_amdgcn_mfma_f32_16x16x32_bf16(
              fa[mi][kk], fb[kk], acc[mi][ni], 0, 0, 0);
      __builtin_amdgcn_s_setprio(0);
      if (ni == 3) {
        // once per K-tile, counted: tile t+1 fully landed, tile t+2's A
        // halves (4 loads) legally stay in flight across the barrier (T4)
        if (t + 2 < NT)
          asm volatile("s_waitcnt vmcnt(4)" ::: "memory");
        else
          asm volatile("s_waitcnt vmcnt(0)" ::: "memory");
      }
      asm volatile("s_barrier" ::: "memory");
    }
  }

  // ---- epilogue: C/D layout col=lane&15, row=(lane>>4)*4+j ----
#pragma unroll
  for (int mi = 0; mi < 8; ++mi) {
#pragma unroll
    for (int ni = 0; ni < 4; ++ni) {
      const int row = row0 + wr * 128 + mi * 16 + lg * 4;  // +j
      const int col = col0 + wc * 64 + ni * 16 + lr;
      if (MODE == 0) {
        uint16_t* C = (uint16_t*)C0;
#pragma unroll
        for (int j = 0; j < 4; ++j)
          C[(long long)(row + j) * N + col] = f2bf(acc[mi][ni][j]);
      } else if (MODE == 1) {
        if (col < 1024) {
          uint16_t* Kp = (uint16_t*)C0;
#pragma unroll
          for (int j = 0; j < 4; ++j)
            Kp[(long long)(row + j) * 1024 + col] = f2bf(acc[mi][ni][j]);
        } else {
          const int b = row >> 10, jj = row & 1023;
          ushort4 o;
          o.x = f2bf(acc[mi][ni][0]);
          o.y = f2bf(acc[mi][ni][1]);
          o.z = f2bf(acc[mi][ni][2]);
          o.w = f2bf(acc[mi][ni][3]);
          uint16_t* Vp = (uint16_t*)C1;
          *(ushort4*)(Vp + (long long)b * 1048576 +
                      (long long)(col - 1024) * 1024 + jj) = o;
        }
      } else {
        float* C = (float*)C0;
#pragma unroll
        for (int j = 0; j < 4; ++j)
          C[(long long)bz * sC + (long long)(row + j) * N + col] =
              acc[mi][ni][j] * scale;
      }
    }
  }
}

// ---- row softmax: 16384 rows x 1024 fp32 -> bf16 ----
__global__ __launch_bounds__(256) void softmax_rows(const float* __restrict__ S,
                                                    uint16_t* __restrict__ P) {
  const int row = blockIdx.x;
  const int t = threadIdx.x;
  const int w = t >> 6, l = t & 63;
  __shared__ float red[8];

  const float4 v = ((const float4*)(S + (long long)row * 1024))[t];
  float m = fmaxf(fmaxf(v.x, v.y), fmaxf(v.z, v.w));
#pragma unroll
  for (int o = 1; o < 64; o <<= 1) m = fmaxf(m, __shfl_xor(m, o, 64));
  if (l == 0) red[w] = m;
  __syncthreads();
  m = fmaxf(fmaxf(red[0], red[1]), fmaxf(red[2], red[3]));

  float e0 = __expf(v.x - m), e1 = __expf(v.y - m);
  float e2 = __expf(v.z - m), e3 = __expf(v.w - m);
  float s = e0 + e1 + e2 + e3;
#pragma unroll
  for (int o = 1; o < 64; o <<= 1) s += __shfl_xor(s, o, 64);
  if (l == 0) red[4 + w] = s;
  __syncthreads();
  s = red[4] + red[5] + red[6] + red[7];
  const float inv = 1.0f / s;

  ushort4 o4;
  o4.x = f2bf(e0 * inv); o4.y = f2bf(e1 * inv);
  o4.z = f2bf(e2 * inv); o4.w = f2bf(e3 * inv);
  ((ushort4*)P)[(long long)row * 256 + t] = o4;
}

extern "C" void kernel_launch(void* const* d_in, const int* in_sizes, int n_in,
                              void* d_out, int out_size, void* d_ws, size_t ws_size,
                              hipStream_t stream) {
  const float* x    = (const float*)d_in[0];
  const float* cond = (const float*)d_in[1];
  const float* Wq   = (const float*)d_in[2];
  const float* Wkv  = (const float*)d_in[3];
  float* out = (float*)d_out;

  uint8_t* ws = (uint8_t*)d_ws;
  const long long MiB = 1ll << 20;
  // layout (166 MiB peak): S(fp32,64Mi) overlays XB+CB; P overlays Q.
  uint16_t* XB   = (uint16_t*)(ws + 0 * MiB);    // 32 MiB
  uint16_t* CB   = (uint16_t*)(ws + 32 * MiB);   // 32 MiB
  float*    S    = (float*)(ws + 0 * MiB);       // 64 MiB (after projections)
  uint16_t* WQB  = (uint16_t*)(ws + 64 * MiB);   // 2 MiB
  uint16_t* WKVB = (uint16_t*)(ws + 66 * MiB);   // 4 MiB
  uint16_t* Q    = (uint16_t*)(ws + 70 * MiB);   // 32 MiB (later P)
  uint16_t* Kb   = (uint16_t*)(ws + 102 * MiB);  // 32 MiB
  uint16_t* VT   = (uint16_t*)(ws + 134 * MiB);  // 32 MiB

  // 1. conversions
  cvt_bf16<<<16384, 256, 0, stream>>>(x, XB, 16777216 / 4);
  cvt_bf16<<<16384, 256, 0, stream>>>(cond, CB, 16777216 / 4);
  cvt_bf16<<<1024, 256, 0, stream>>>(Wq, WQB, 1048576 / 4);
  cvt_bf16<<<2048, 256, 0, stream>>>(Wkv, WKVB, 2097152 / 4);

  // 2. Q = XB @ WQB^T   (M=16384, N=1024, K=1024) -> 256 blocks (1/CU)
  gemm_bt<0><<<dim3(4, 64, 1), 512, 0, stream>>>(XB, WQB, Q, nullptr, 1024,
                                                 1024, 0, 0, 0, 1.0f);
  // 3. KV = CB @ WKVB^T (M=16384, N=2048) -> K, V^T  (512 blocks)
  gemm_bt<1><<<dim3(8, 64, 1), 512, 0, stream>>>(CB, WKVB, Kb, VT, 1024, 2048,
                                                 0, 0, 0, 1.0f);
  // 4. S = Q @ K^T * 1/32, batched over 16 (256 blocks)
  gemm_bt<2><<<dim3(4, 4, 16), 512, 0, stream>>>(Q, Kb, S, nullptr, 1024, 1024,
                                                 1048576, 1048576, 1048576,
                                                 0.03125f);
  // 5. P = softmax(S) -> bf16, overlays Q
  softmax_rows<<<16384, 256, 0, stream>>>(S, Q);
  // 6. out = P @ (V^T)^T, batched over 16 (256 blocks)
  gemm_bt<2><<<dim3(4, 4, 16), 512, 0, stream>>>(Q, VT, out, nullptr, 1024,
                                                 1024, 1048576, 1048576,
                                                 1048576, 1.0f);
}

// Round 3
// 256.930 us; speedup vs baseline: 1.1602x; 1.0477x over previous
//
#include <hip/hip_runtime.h>
#include <stdint.h>

// ---------------------------------------------------------------------------
// CrossAttention (b=16, c=1024, dim=1024), fp32 in/out, bf16 MFMA internally.
//   1. cvt fp32->bf16: x->XB, cond->CB, Wq->WQB, Wkv->WKVB
//   2. Q  = XB @ WQB^T                      (bf16 out)
//   3. KV = CB @ WKVB^T  -> K (bf16), V^T   (bf16, transposed in epilogue)
//   4. S  = Q @ K^T * 1/32  per batch       (fp32, overlays XB/CB)
//   5. P  = softmax_rows(S)                 (bf16, overlays Q)
//   6. out= P @ (V^T)^T  per batch          (fp32 -> d_out)
// GEMM: m201-style 256x256 tile, BK=64, 8 waves (2Mx4N), 8 phases per
// iteration (2 K-tiles), derived counted vmcnt(4), lgkmcnt(0)+sched_barrier
// before each MFMA cluster (rule #18), XOR-swizzled LDS, setprio, XCD swizzle.
// ---------------------------------------------------------------------------

typedef __bf16 bf16_t;
typedef bf16_t bf16x8 __attribute__((ext_vector_type(8)));
typedef float f32x4 __attribute__((ext_vector_type(4)));

#define AS1 __attribute__((address_space(1)))
#define AS3 __attribute__((address_space(3)))

__device__ __forceinline__ uint16_t f2bf(float f) {
  bf16_t h = (bf16_t)f;  // RNE
  return __builtin_bit_cast(uint16_t, h);
}

// ---- fp32 -> bf16 conversion, float4-vectorized ----
__global__ __launch_bounds__(256) void cvt_bf16(const float* __restrict__ in,
                                                uint16_t* __restrict__ out, int n4) {
  int i = blockIdx.x * 256 + threadIdx.x;
  if (i >= n4) return;
  float4 v = ((const float4*)in)[i];
  ushort4 o;
  o.x = f2bf(v.x); o.y = f2bf(v.y); o.z = f2bf(v.z); o.w = f2bf(v.w);
  ((ushort4*)out)[i] = o;
}

// ---- stage one 128x64 bf16 half-tile (16 KiB) global -> LDS ----
// LDS dest linear (global_load_lds requirement); global SOURCE chunk-XOR
// pre-swizzled (rule #21) so readers use byte^=((row&7)<<4), conflict-free.
// 512 threads x 2 chunks x 16B. 2 vmem ops per thread per call.
__device__ __forceinline__ void stage_half(const uint16_t* __restrict__ g, int ld,
                                           uint8_t* lds, int tid) {
#pragma unroll
  for (int i = 0; i < 2; ++i) {
    int c = i * 512 + tid;              // 16B-chunk index, 0..1023
    int row = c >> 3;                   // 0..127
    int ch = c & 7;                     // chunk within 128B row
    int sch = ch ^ (row & 7);           // involutive source swizzle
    const uint16_t* gp = g + row * ld + sch * 8;
    __builtin_amdgcn_global_load_lds((AS1 void*)gp, (AS3 void*)(lds + c * 16),
                                     16, 0, 0);
  }
}

// One phase: ds_reads (optional) | stage one half-tile | BAR | lgkm0+SGB |
// prio1 | 16 MFMA (quadrant H,N2 of tile in AB/BB) | prio0 | [vm wait] | BAR
#define PH(AB, BB, H, N2, DO_A, DO_B, STAGE, VMW)                              \
  {                                                                            \
    if (DO_A) {                                                                \
      _Pragma("unroll") for (int mi = 0; mi < 4; ++mi)                         \
          _Pragma("unroll") for (int kk = 0; kk < 2; ++kk)                     \
              aF[mi][kk] = *(const bf16x8*)((AB) + ((H)*64 + mi*16 + lr)*128 + \
                                            (((kk*4 + lg) ^ ch0) << 4));       \
    }                                                                          \
    if (DO_B) {                                                                \
      _Pragma("unroll") for (int nj = 0; nj < 2; ++nj)                         \
          _Pragma("unroll") for (int kk = 0; kk < 2; ++kk)                     \
              bAll[(N2)*2 + nj][kk] = *(const bf16x8*)(                        \
                  (BB) + ((wc & 1)*64 + ((N2)*2 + nj)*16 + lr)*128 +           \
                  (((kk*4 + lg) ^ ch0) << 4));                                 \
    }                                                                          \
    STAGE;                                                                     \
    asm volatile("s_barrier" ::: "memory");                                    \
    asm volatile("s_waitcnt lgkmcnt(0)" ::: "memory");                         \
    __builtin_amdgcn_sched_barrier(0);                                         \
    __builtin_amdgcn_s_setprio(1);                                             \
    _Pragma("unroll") for (int kk = 0; kk < 2; ++kk)                           \
        _Pragma("unroll") for (int mi = 0; mi < 4; ++mi)                       \
            _Pragma("unroll") for (int nj = 0; nj < 2; ++nj)                   \
                acc[(H)*4 + mi][(N2)*2 + nj] =                                 \
                    __builtin_amdgcn_mfma_f32_16x16x32_bf16(                   \
                        aF[mi][kk], bAll[(N2)*2 + nj][kk],                     \
                        acc[(H)*4 + mi][(N2)*2 + nj], 0, 0, 0);                \
    __builtin_amdgcn_s_setprio(0);                                             \
    VMW;                                                                       \
    asm volatile("s_barrier" ::: "memory");                                    \
  }

// ---- 256x256-tile A·B^T GEMM, bf16 in, fp32 accum, 8-phase pipelined ----
// MODE 0: C0 = bf16, ldc = N
// MODE 1: kv-split: col<1024 -> K (bf16 row-major); col>=1024 -> V^T
// MODE 2: C0 = fp32 * scale, batched via blockIdx.z (strides in elements)
template <int MODE>
__global__ __launch_bounds__(512, 2) void gemm_bt(
    const uint16_t* __restrict__ A, const uint16_t* __restrict__ B,
    void* __restrict__ C0, void* __restrict__ C1, int K, int N,
    long long sA, long long sB, long long sC, float scale) {
  // buf0 <-> even K-tiles, buf1 <-> odd K-tiles (fixed mapping, no flip)
  __shared__ uint16_t As[2][2][8192];  // [buf][half(rows wr*128..)][128x64]
  __shared__ uint16_t Bs[2][2][8192];  // [buf][half(cols .. )][128x64]

  const int tid = threadIdx.x;
  const int lane = tid & 63;
  const int wid = tid >> 6;   // 0..7
  const int wr = wid >> 2;    // 0..1 : M wave row (128 rows each)
  const int wc = wid & 3;     // 0..3 : N wave col (64 cols each)
  const int lr = lane & 15, lg = lane >> 4;
  const int ch0 = lr & 7;     // reader swizzle parity (== row&7 for all frags)

  // T1: bijective XCD-chunked blockIdx swizzle (nwg % 8 == 0 for all grids)
  const int gx = gridDim.x, gy = gridDim.y;
  const int nwg = gx * gy * gridDim.z;
  int fid = blockIdx.x + gx * (blockIdx.y + gy * blockIdx.z);
  int swz = (fid & 7) * (nwg >> 3) + (fid >> 3);
  const int bx = swz % gx;
  const int rem = swz / gx;
  const int by = rem % gy;
  const int bz = rem / gy;

  const int row0 = by * 256;
  const int col0 = bx * 256;
  const uint16_t* At = A + (long long)bz * sA + (long long)row0 * K;
  const uint16_t* Bt = B + (long long)bz * sB + (long long)col0 * K;

  const int NT = K >> 6;    // 64-wide K-tiles (16 here)
  const int NIT = NT >> 1;  // iterations (2 tiles each)

  // ---- prologue ("iteration -1" ph2..ph7): buf0 full (t0), buf1.B (t1) ----
  stage_half(Bt, K, (uint8_t*)&Bs[0][0][0], tid);
  stage_half(Bt + 128 * K, K, (uint8_t*)&Bs[0][1][0], tid);
  stage_half(At, K, (uint8_t*)&As[0][0][0], tid);
  stage_half(At + 128 * K, K, (uint8_t*)&As[0][1][0], tid);
  stage_half(Bt + 64, K, (uint8_t*)&Bs[1][0][0], tid);
  stage_half(Bt + 128 * K + 64, K, (uint8_t*)&Bs[1][1][0], tid);
  asm volatile("s_waitcnt vmcnt(4)" ::: "memory");  // buf0 landed; buf1.B flies
  asm volatile("s_barrier" ::: "memory");

  f32x4 acc[8][4] = {};
  bf16x8 aF[4][2];    // current mi-half fragments
  bf16x8 bAll[4][2];  // all 4 ni fragments of current tile

  for (int i = 0; i < NIT; ++i) {
    const int t1 = 2 * i + 1;
    const int tn0 = 2 * i + 2, tn1 = 2 * i + 3;  // refill targets
    const uint8_t* a0 = (const uint8_t*)&As[0][wr][0];
    const uint8_t* a1 = (const uint8_t*)&As[1][wr][0];
    const uint8_t* b0 = (const uint8_t*)&Bs[0][wc >> 1][0];
    const uint8_t* b1 = (const uint8_t*)&Bs[1][wc >> 1][0];

    // ph0: tile t0 (h0,n2=0), 12 reads; stage buf1.A-lo(t1)
    PH(a0, b0, 0, 0, true, true,
       stage_half(At + t1 * 64, K, (uint8_t*)&As[1][0][0], tid), );
    // ph1: (h0,n2=1), 4 reads; stage buf1.A-hi(t1)
    PH(a0, b0, 0, 1, false, true,
       stage_half(At + 128 * K + t1 * 64, K, (uint8_t*)&As[1][1][0], tid), );
    // ph2: (h1,n2=0), 8 reads; stage buf0.B-lo(t0+2)
    PH(a0, b0, 1, 0, true, false,
       if (tn0 < NT) stage_half(Bt + tn0 * 64, K, (uint8_t*)&Bs[0][0][0], tid), );
    // ph3: (h1,n2=1), 0 reads; stage buf0.B-hi(t0+2); derived vm wait
    PH(a0, b0, 1, 1, false, false,
       if (tn0 < NT) stage_half(Bt + 128 * K + tn0 * 64, K,
                                (uint8_t*)&Bs[0][1][0], tid),
       if (i + 1 < NIT) asm volatile("s_waitcnt vmcnt(4)" ::: "memory");
       else asm volatile("s_waitcnt vmcnt(0)" ::: "memory"));
    // ph4: tile t1 (h0,n2=0); stage buf0.A-lo(t0+2)
    PH(a1, b1, 0, 0, true, true,
       if (tn0 < NT) stage_half(At + tn0 * 64, K, (uint8_t*)&As[0][0][0], tid), );
    // ph5: (h0,n2=1); stage buf0.A-hi(t0+2)
    PH(a1, b1, 0, 1, false, true,
       if (tn0 < NT) stage_half(At + 128 * K + tn0 * 64, K,
                                (uint8_t*)&As[0][1][0], tid), );
    // ph6: (h1,n2=0); stage buf1.B-lo(t1+2)
    PH(a1, b1, 1, 0, true, false,
       if (tn1 < NT) stage_half(Bt + tn1 * 64, K, (uint8_t*)&Bs[1][0][0], tid), );
    // ph7: (h1,n2=1); stage buf1.B-hi(t1+2); derived vm wait
    PH(a1, b1, 1, 1, false, false,
       if (tn1 < NT) stage_half(Bt + 128 * K + tn1 * 64, K,
                                (uint8_t*)&Bs[1][1][0], tid),
       if (i + 1 < NIT) asm volatile("s_waitcnt vmcnt(4)" ::: "memory");
       else asm volatile("s_waitcnt vmcnt(0)" ::: "memory"));
  }

  // ---- epilogue: C/D layout col=lane&15, row=(lane>>4)*4+j ----
#pragma unroll
  for (int mi = 0; mi < 8; ++mi) {
#pragma unroll
    for (int ni = 0; ni < 4; ++ni) {
      const int row = row0 + wr * 128 + mi * 16 + lg * 4;  // +j
      const int col = col0 + wc * 64 + ni * 16 + lr;
      if (MODE == 0) {
        uint16_t* C = (uint16_t*)C0;
#pragma unroll
        for (int j = 0; j < 4; ++j)
          C[(long long)(row + j) * N + col] = f2bf(acc[mi][ni][j]);
      } else if (MODE == 1) {
        if (col < 1024) {
          uint16_t* Kp = (uint16_t*)C0;
#pragma unroll
          for (int j = 0; j < 4; ++j)
            Kp[(long long)(row + j) * 1024 + col] = f2bf(acc[mi][ni][j]);
        } else {
          const int b = row >> 10, jj = row & 1023;
          ushort4 o;
          o.x = f2bf(acc[mi][ni][0]);
          o.y = f2bf(acc[mi][ni][1]);
          o.z = f2bf(acc[mi][ni][2]);
          o.w = f2bf(acc[mi][ni][3]);
          uint16_t* Vp = (uint16_t*)C1;
          *(ushort4*)(Vp + (long long)b * 1048576 +
                      (long long)(col - 1024) * 1024 + jj) = o;
        }
      } else {
        float* C = (float*)C0;
#pragma unroll
        for (int j = 0; j < 4; ++j)
          C[(long long)bz * sC + (long long)(row + j) * N + col] =
              acc[mi][ni][j] * scale;
      }
    }
  }
}

// ---- row softmax: 16384 rows x 1024 fp32 -> bf16 ----
__global__ __launch_bounds__(256) void softmax_rows(const float* __restrict__ S,
                                                    uint16_t* __restrict__ P) {
  const int row = blockIdx.x;
  const int t = threadIdx.x;
  const int w = t >> 6, l = t & 63;
  __shared__ float red[8];

  const float4 v = ((const float4*)(S + (long long)row * 1024))[t];
  float m = fmaxf(fmaxf(v.x, v.y), fmaxf(v.z, v.w));
#pragma unroll
  for (int o = 1; o < 64; o <<= 1) m = fmaxf(m, __shfl_xor(m, o, 64));
  if (l == 0) red[w] = m;
  __syncthreads();
  m = fmaxf(fmaxf(red[0], red[1]), fmaxf(red[2], red[3]));

  float e0 = __expf(v.x - m), e1 = __expf(v.y - m);
  float e2 = __expf(v.z - m), e3 = __expf(v.w - m);
  float s = e0 + e1 + e2 + e3;
#pragma unroll
  for (int o = 1; o < 64; o <<= 1) s += __shfl_xor(s, o, 64);
  if (l == 0) red[4 + w] = s;
  __syncthreads();
  s = red[4] + red[5] + red[6] + red[7];
  const float inv = 1.0f / s;

  ushort4 o4;
  o4.x = f2bf(e0 * inv); o4.y = f2bf(e1 * inv);
  o4.z = f2bf(e2 * inv); o4.w = f2bf(e3 * inv);
  ((ushort4*)P)[(long long)row * 256 + t] = o4;
}

extern "C" void kernel_launch(void* const* d_in, const int* in_sizes, int n_in,
                              void* d_out, int out_size, void* d_ws, size_t ws_size,
                              hipStream_t stream) {
  const float* x    = (const float*)d_in[0];
  const float* cond = (const float*)d_in[1];
  const float* Wq   = (const float*)d_in[2];
  const float* Wkv  = (const float*)d_in[3];
  float* out = (float*)d_out;

  uint8_t* ws = (uint8_t*)d_ws;
  const long long MiB = 1ll << 20;
  // layout (166 MiB peak): S(fp32,64Mi) overlays XB+CB; P overlays Q.
  uint16_t* XB   = (uint16_t*)(ws + 0 * MiB);    // 32 MiB
  uint16_t* CB   = (uint16_t*)(ws + 32 * MiB);   // 32 MiB
  float*    S    = (float*)(ws + 0 * MiB);       // 64 MiB (after projections)
  uint16_t* WQB  = (uint16_t*)(ws + 64 * MiB);   // 2 MiB
  uint16_t* WKVB = (uint16_t*)(ws + 66 * MiB);   // 4 MiB
  uint16_t* Q    = (uint16_t*)(ws + 70 * MiB);   // 32 MiB (later P)
  uint16_t* Kb   = (uint16_t*)(ws + 102 * MiB);  // 32 MiB
  uint16_t* VT   = (uint16_t*)(ws + 134 * MiB);  // 32 MiB

  // 1. conversions
  cvt_bf16<<<16384, 256, 0, stream>>>(x, XB, 16777216 / 4);
  cvt_bf16<<<16384, 256, 0, stream>>>(cond, CB, 16777216 / 4);
  cvt_bf16<<<1024, 256, 0, stream>>>(Wq, WQB, 1048576 / 4);
  cvt_bf16<<<2048, 256, 0, stream>>>(Wkv, WKVB, 2097152 / 4);

  // 2. Q = XB @ WQB^T   (M=16384, N=1024, K=1024) -> 256 blocks (1/CU)
  gemm_bt<0><<<dim3(4, 64, 1), 512, 0, stream>>>(XB, WQB, Q, nullptr, 1024,
                                                 1024, 0, 0, 0, 1.0f);
  // 3. KV = CB @ WKVB^T (M=16384, N=2048) -> K, V^T  (512 blocks)
  gemm_bt<1><<<dim3(8, 64, 1), 512, 0, stream>>>(CB, WKVB, Kb, VT, 1024, 2048,
                                                 0, 0, 0, 1.0f);
  // 4. S = Q @ K^T * 1/32, batched over 16 (256 blocks)
  gemm_bt<2><<<dim3(4, 4, 16), 512, 0, stream>>>(Q, Kb, S, nullptr, 1024, 1024,
                                                 1048576, 1048576, 1048576,
                                                 0.03125f);
  // 5. P = softmax(S) -> bf16, overlays Q
  softmax_rows<<<16384, 256, 0, stream>>>(S, Q);
  // 6. out = P @ (V^T)^T, batched over 16 (256 blocks)
  gemm_bt<2><<<dim3(4, 4, 16), 512, 0, stream>>>(Q, VT, out, nullptr, 1024,
                                                 1024, 1048576, 1048576,
                                                 1048576, 1.0f);
}

// Round 4
// 254.096 us; speedup vs baseline: 1.1731x; 1.0112x over previous
//
#include <hip/hip_runtime.h>
#include <stdint.h>

// ---------------------------------------------------------------------------
// CrossAttention (b=16, c=1024, dim=1024), fp32 in/out, bf16 MFMA internally.
//   1. cvt fp32->bf16: x->XB, cond->CB, Wq->WQB, Wkv->WKVB
//   2. Q  = XB @ WQB^T                      (bf16 out)
//   3. KV = CB @ WKVB^T  -> K (bf16), V^T   (bf16, transposed in epilogue)
//   4. S  = Q @ K^T * 1/32  per batch       (fp32, overlays XB/CB)
//   5. P  = softmax_rows(S)                 (bf16, overlays Q)
//   6. out= P @ (V^T)^T  per batch          (fp32 -> d_out)
// GEMM: 256x256 tile, BK=64, 8 waves (2Mx4N), 8 phases / 2 K-tiles, counted
// vmcnt(4) (T4), XOR-swizzled LDS (T2), setprio (T5), XCD swizzle (T1).
// R4: fences minimized — no lgkmcnt(0)/sched_barrier order-pinning (m141);
// compiler handles ds_read->MFMA waits; only vmcnt asm carries "memory".
// ---------------------------------------------------------------------------

typedef __bf16 bf16_t;
typedef bf16_t bf16x8 __attribute__((ext_vector_type(8)));
typedef float f32x4 __attribute__((ext_vector_type(4)));

#define AS1 __attribute__((address_space(1)))
#define AS3 __attribute__((address_space(3)))

__device__ __forceinline__ uint16_t f2bf(float f) {
  bf16_t h = (bf16_t)f;  // RNE
  return __builtin_bit_cast(uint16_t, h);
}

// ---- fp32 -> bf16 conversion, float4-vectorized ----
__global__ __launch_bounds__(256) void cvt_bf16(const float* __restrict__ in,
                                                uint16_t* __restrict__ out, int n4) {
  int i = blockIdx.x * 256 + threadIdx.x;
  if (i >= n4) return;
  float4 v = ((const float4*)in)[i];
  ushort4 o;
  o.x = f2bf(v.x); o.y = f2bf(v.y); o.z = f2bf(v.z); o.w = f2bf(v.w);
  ((ushort4*)out)[i] = o;
}

// ---- stage one 128x64 bf16 half-tile (16 KiB) global -> LDS ----
// LDS dest linear (global_load_lds requirement); global SOURCE chunk-XOR
// pre-swizzled (rule #21) so readers use byte^=((row&7)<<4), conflict-free.
__device__ __forceinline__ void stage_half(const uint16_t* __restrict__ g, int ld,
                                           uint8_t* lds, int tid) {
#pragma unroll
  for (int i = 0; i < 2; ++i) {
    int c = i * 512 + tid;              // 16B-chunk index, 0..1023
    int row = c >> 3;                   // 0..127
    int ch = c & 7;                     // chunk within 128B row
    int sch = ch ^ (row & 7);           // involutive source swizzle
    const uint16_t* gp = g + row * ld + sch * 8;
    __builtin_amdgcn_global_load_lds((AS1 void*)gp, (AS3 void*)(lds + c * 16),
                                     16, 0, 0);
  }
}

// One phase: ds_reads (plain, compiler-scheduled) | stage one half-tile |
// BAR | prio1 | 16 MFMA | prio0 | [counted vm wait] | BAR
#define PH(AB, BB, H, N2, DO_A, DO_B, STAGE, VMW)                              \
  {                                                                            \
    if (DO_A) {                                                                \
      _Pragma("unroll") for (int mi = 0; mi < 4; ++mi)                         \
          _Pragma("unroll") for (int kk = 0; kk < 2; ++kk)                     \
              aF[mi][kk] = *(const bf16x8*)((AB) + ((H)*64 + mi*16 + lr)*128 + \
                                            (((kk*4 + lg) ^ ch0) << 4));       \
    }                                                                          \
    if (DO_B) {                                                                \
      _Pragma("unroll") for (int nj = 0; nj < 2; ++nj)                         \
          _Pragma("unroll") for (int kk = 0; kk < 2; ++kk)                     \
              bAll[(N2)*2 + nj][kk] = *(const bf16x8*)(                        \
                  (BB) + ((wc & 1)*64 + ((N2)*2 + nj)*16 + lr)*128 +           \
                  (((kk*4 + lg) ^ ch0) << 4));                                 \
    }                                                                          \
    STAGE;                                                                     \
    __builtin_amdgcn_s_barrier();                                              \
    __builtin_amdgcn_s_setprio(1);                                             \
    _Pragma("unroll") for (int kk = 0; kk < 2; ++kk)                           \
        _Pragma("unroll") for (int mi = 0; mi < 4; ++mi)                       \
            _Pragma("unroll") for (int nj = 0; nj < 2; ++nj)                   \
                acc[(H)*4 + mi][(N2)*2 + nj] =                                 \
                    __builtin_amdgcn_mfma_f32_16x16x32_bf16(                   \
                        aF[mi][kk], bAll[(N2)*2 + nj][kk],                     \
                        acc[(H)*4 + mi][(N2)*2 + nj], 0, 0, 0);                \
    __builtin_amdgcn_s_setprio(0);                                             \
    VMW;                                                                       \
    __builtin_amdgcn_s_barrier();                                              \
  }

// ---- 256x256-tile A·B^T GEMM, bf16 in, fp32 accum, 8-phase pipelined ----
// MODE 0: C0 = bf16, ldc = N
// MODE 1: kv-split: col<1024 -> K (bf16 row-major); col>=1024 -> V^T
// MODE 2: C0 = fp32 * scale, batched via blockIdx.z (strides in elements)
template <int MODE>
__global__ __launch_bounds__(512, 2) void gemm_bt(
    const uint16_t* __restrict__ A, const uint16_t* __restrict__ B,
    void* __restrict__ C0, void* __restrict__ C1, int K, int N,
    long long sA, long long sB, long long sC, float scale) {
  // buf0 <-> even K-tiles, buf1 <-> odd K-tiles (fixed mapping, no flip)
  __shared__ uint16_t As[2][2][8192];  // [buf][half(rows wr*128..)][128x64]
  __shared__ uint16_t Bs[2][2][8192];  // [buf][half(cols .. )][128x64]

  const int tid = threadIdx.x;
  const int lane = tid & 63;
  const int wid = tid >> 6;   // 0..7
  const int wr = wid >> 2;    // 0..1 : M wave row (128 rows each)
  const int wc = wid & 3;     // 0..3 : N wave col (64 cols each)
  const int lr = lane & 15, lg = lane >> 4;
  const int ch0 = lr & 7;     // reader swizzle parity (== row&7 for all frags)

  // T1: bijective XCD-chunked blockIdx swizzle (nwg % 8 == 0 for all grids)
  const int gx = gridDim.x, gy = gridDim.y;
  const int nwg = gx * gy * gridDim.z;
  int fid = blockIdx.x + gx * (blockIdx.y + gy * blockIdx.z);
  int swz = (fid & 7) * (nwg >> 3) + (fid >> 3);
  const int bx = swz % gx;
  const int rem = swz / gx;
  const int by = rem % gy;
  const int bz = rem / gy;

  const int row0 = by * 256;
  const int col0 = bx * 256;
  const uint16_t* At = A + (long long)bz * sA + (long long)row0 * K;
  const uint16_t* Bt = B + (long long)bz * sB + (long long)col0 * K;

  const int NT = K >> 6;    // 64-wide K-tiles (16 here)
  const int NIT = NT >> 1;  // iterations (2 tiles each)

  // ---- prologue: buf0 full (t0) + buf1.B (t1) = 6 half-tiles, 12 loads ----
  stage_half(Bt, K, (uint8_t*)&Bs[0][0][0], tid);
  stage_half(Bt + 128 * K, K, (uint8_t*)&Bs[0][1][0], tid);
  stage_half(At, K, (uint8_t*)&As[0][0][0], tid);
  stage_half(At + 128 * K, K, (uint8_t*)&As[0][1][0], tid);
  stage_half(Bt + 64, K, (uint8_t*)&Bs[1][0][0], tid);
  stage_half(Bt + 128 * K + 64, K, (uint8_t*)&Bs[1][1][0], tid);
  asm volatile("s_waitcnt vmcnt(4)" ::: "memory");  // buf0 landed; buf1.B flies
  __builtin_amdgcn_s_barrier();

  f32x4 acc[8][4] = {};
  bf16x8 aF[4][2];    // current mi-half fragments
  bf16x8 bAll[4][2];  // all 4 ni fragments of current tile

  for (int i = 0; i < NIT; ++i) {
    const int t1 = 2 * i + 1;
    const int tn0 = 2 * i + 2, tn1 = 2 * i + 3;  // refill targets
    const uint8_t* a0 = (const uint8_t*)&As[0][wr][0];
    const uint8_t* a1 = (const uint8_t*)&As[1][wr][0];
    const uint8_t* b0 = (const uint8_t*)&Bs[0][wc >> 1][0];
    const uint8_t* b1 = (const uint8_t*)&Bs[1][wc >> 1][0];

    // ph0: tile t0 (h0,n2=0), 12 reads; stage buf1.A-lo(t1)
    PH(a0, b0, 0, 0, true, true,
       stage_half(At + t1 * 64, K, (uint8_t*)&As[1][0][0], tid), );
    // ph1: (h0,n2=1), 4 reads; stage buf1.A-hi(t1)
    PH(a0, b0, 0, 1, false, true,
       stage_half(At + 128 * K + t1 * 64, K, (uint8_t*)&As[1][1][0], tid), );
    // ph2: (h1,n2=0), 8 reads; stage buf0.B-lo(t0+2)
    PH(a0, b0, 1, 0, true, false,
       if (tn0 < NT) stage_half(Bt + tn0 * 64, K, (uint8_t*)&Bs[0][0][0], tid), );
    // ph3: (h1,n2=1), 0 reads; stage buf0.B-hi(t0+2); derived vm wait
    PH(a0, b0, 1, 1, false, false,
       if (tn0 < NT) stage_half(Bt + 128 * K + tn0 * 64, K,
                                (uint8_t*)&Bs[0][1][0], tid),
       if (i + 1 < NIT) asm volatile("s_waitcnt vmcnt(4)" ::: "memory");
       else asm volatile("s_waitcnt vmcnt(0)" ::: "memory"));
    // ph4: tile t1 (h0,n2=0); stage buf0.A-lo(t0+2)
    PH(a1, b1, 0, 0, true, true,
       if (tn0 < NT) stage_half(At + tn0 * 64, K, (uint8_t*)&As[0][0][0], tid), );
    // ph5: (h0,n2=1); stage buf0.A-hi(t0+2)
    PH(a1, b1, 0, 1, false, true,
       if (tn0 < NT) stage_half(At + 128 * K + tn0 * 64, K,
                                (uint8_t*)&As[0][1][0], tid), );
    // ph6: (h1,n2=0); stage buf1.B-lo(t1+2)
    PH(a1, b1, 1, 0, true, false,
       if (tn1 < NT) stage_half(Bt + tn1 * 64, K, (uint8_t*)&Bs[1][0][0], tid), );
    // ph7: (h1,n2=1); stage buf1.B-hi(t1+2); derived vm wait
    PH(a1, b1, 1, 1, false, false,
       if (tn1 < NT) stage_half(Bt + 128 * K + tn1 * 64, K,
                                (uint8_t*)&Bs[1][1][0], tid),
       if (i + 1 < NIT) asm volatile("s_waitcnt vmcnt(4)" ::: "memory");
       else asm volatile("s_waitcnt vmcnt(0)" ::: "memory"));
  }

  // ---- epilogue: C/D layout col=lane&15, row=(lane>>4)*4+j ----
#pragma unroll
  for (int mi = 0; mi < 8; ++mi) {
#pragma unroll
    for (int ni = 0; ni < 4; ++ni) {
      const int row = row0 + wr * 128 + mi * 16 + lg * 4;  // +j
      const int col = col0 + wc * 64 + ni * 16 + lr;
      if (MODE == 0) {
        uint16_t* C = (uint16_t*)C0;
#pragma unroll
        for (int j = 0; j < 4; ++j)
          C[(long long)(row + j) * N + col] = f2bf(acc[mi][ni][j]);
      } else if (MODE == 1) {
        if (col < 1024) {
          uint16_t* Kp = (uint16_t*)C0;
#pragma unroll
          for (int j = 0; j < 4; ++j)
            Kp[(long long)(row + j) * 1024 + col] = f2bf(acc[mi][ni][j]);
        } else {
          const int b = row >> 10, jj = row & 1023;
          ushort4 o;
          o.x = f2bf(acc[mi][ni][0]);
          o.y = f2bf(acc[mi][ni][1]);
          o.z = f2bf(acc[mi][ni][2]);
          o.w = f2bf(acc[mi][ni][3]);
          uint16_t* Vp = (uint16_t*)C1;
          *(ushort4*)(Vp + (long long)b * 1048576 +
                      (long long)(col - 1024) * 1024 + jj) = o;
        }
      } else {
        float* C = (float*)C0;
#pragma unroll
        for (int j = 0; j < 4; ++j)
          C[(long long)bz * sC + (long long)(row + j) * N + col] =
              acc[mi][ni][j] * scale;
      }
    }
  }
}

// ---- row softmax: 16384 rows x 1024 fp32 -> bf16 ----
__global__ __launch_bounds__(256) void softmax_rows(const float* __restrict__ S,
                                                    uint16_t* __restrict__ P) {
  const int row = blockIdx.x;
  const int t = threadIdx.x;
  const int w = t >> 6, l = t & 63;
  __shared__ float red[8];

  const float4 v = ((const float4*)(S + (long long)row * 1024))[t];
  float m = fmaxf(fmaxf(v.x, v.y), fmaxf(v.z, v.w));
#pragma unroll
  for (int o = 1; o < 64; o <<= 1) m = fmaxf(m, __shfl_xor(m, o, 64));
  if (l == 0) red[w] = m;
  __syncthreads();
  m = fmaxf(fmaxf(red[0], red[1]), fmaxf(red[2], red[3]));

  float e0 = __expf(v.x - m), e1 = __expf(v.y - m);
  float e2 = __expf(v.z - m), e3 = __expf(v.w - m);
  float s = e0 + e1 + e2 + e3;
#pragma unroll
  for (int o = 1; o < 64; o <<= 1) s += __shfl_xor(s, o, 64);
  if (l == 0) red[4 + w] = s;
  __syncthreads();
  s = red[4] + red[5] + red[6] + red[7];
  const float inv = 1.0f / s;

  ushort4 o4;
  o4.x = f2bf(e0 * inv); o4.y = f2bf(e1 * inv);
  o4.z = f2bf(e2 * inv); o4.w = f2bf(e3 * inv);
  ((ushort4*)P)[(long long)row * 256 + t] = o4;
}

extern "C" void kernel_launch(void* const* d_in, const int* in_sizes, int n_in,
                              void* d_out, int out_size, void* d_ws, size_t ws_size,
                              hipStream_t stream) {
  const float* x    = (const float*)d_in[0];
  const float* cond = (const float*)d_in[1];
  const float* Wq   = (const float*)d_in[2];
  const float* Wkv  = (const float*)d_in[3];
  float* out = (float*)d_out;

  uint8_t* ws = (uint8_t*)d_ws;
  const long long MiB = 1ll << 20;
  // layout (166 MiB peak): S(fp32,64Mi) overlays XB+CB; P overlays Q.
  uint16_t* XB   = (uint16_t*)(ws + 0 * MiB);    // 32 MiB
  uint16_t* CB   = (uint16_t*)(ws + 32 * MiB);   // 32 MiB
  float*    S    = (float*)(ws + 0 * MiB);       // 64 MiB (after projections)
  uint16_t* WQB  = (uint16_t*)(ws + 64 * MiB);   // 2 MiB
  uint16_t* WKVB = (uint16_t*)(ws + 66 * MiB);   // 4 MiB
  uint16_t* Q    = (uint16_t*)(ws + 70 * MiB);   // 32 MiB (later P)
  uint16_t* Kb   = (uint16_t*)(ws + 102 * MiB);  // 32 MiB
  uint16_t* VT   = (uint16_t*)(ws + 134 * MiB);  // 32 MiB

  // 1. conversions
  cvt_bf16<<<16384, 256, 0, stream>>>(x, XB, 16777216 / 4);
  cvt_bf16<<<16384, 256, 0, stream>>>(cond, CB, 16777216 / 4);
  cvt_bf16<<<1024, 256, 0, stream>>>(Wq, WQB, 1048576 / 4);
  cvt_bf16<<<2048, 256, 0, stream>>>(Wkv, WKVB, 2097152 / 4);

  // 2. Q = XB @ WQB^T   (M=16384, N=1024, K=1024) -> 256 blocks (1/CU)
  gemm_bt<0><<<dim3(4, 64, 1), 512, 0, stream>>>(XB, WQB, Q, nullptr, 1024,
                                                 1024, 0, 0, 0, 1.0f);
  // 3. KV = CB @ WKVB^T (M=16384, N=2048) -> K, V^T  (512 blocks)
  gemm_bt<1><<<dim3(8, 64, 1), 512, 0, stream>>>(CB, WKVB, Kb, VT, 1024, 2048,
                                                 0, 0, 0, 1.0f);
  // 4. S = Q @ K^T * 1/32, batched over 16 (256 blocks)
  gemm_bt<2><<<dim3(4, 4, 16), 512, 0, stream>>>(Q, Kb, S, nullptr, 1024, 1024,
                                                 1048576, 1048576, 1048576,
                                                 0.03125f);
  // 5. P = softmax(S) -> bf16, overlays Q
  softmax_rows<<<16384, 256, 0, stream>>>(S, Q);
  // 6. out = P @ (V^T)^T, batched over 16 (256 blocks)
  gemm_bt<2><<<dim3(4, 4, 16), 512, 0, stream>>>(Q, VT, out, nullptr, 1024,
                                                 1024, 1048576, 1048576,
                                                 1048576, 1.0f);
}